// Round 10
// baseline (149.840 us; speedup 1.0000x reference)
//
#include <hip/hip_runtime.h>

// PointnetFPModule: three_nn (brute force, top-3 smallest d2) + three_interpolate.
// Shapes: B=8, N=8192, M=2048, C=256.  All fp32.
// unknown (B,N,3), known (B,M,3), known_feats (B,C,M) -> out (B,C,N)
//
// R9 (resubmit; R9 bench was a broker timeout): R8 scan was LDS-issue-bound
// (2 passes x 4 arrays of broadcast ds_read_b128 ~ 80us of LDS pipe per CU).
// Candidates are wave-uniform -> move them to the SCALAR path: prep kernel
// packs (x,y,z,|k|^2) float4; scan s_load_dwordx16's them into SGPRs (inline
// asm), VALU ops take one SGPR operand each. LDS only for 9.5KB merge
// scratch -> 32 waves/CU.
// Two-pass threshold scan kept: stage1 r=|k|^2-2u.k (3 FMA) + med3/med3/min;
// T = 3rd-smallest r + 1e-4 (margin >> 1.4e-6 rounding bound); stage2
// recomputes r bit-identically (same SGPRs), rare branch computes canonical
// no-FMA (x2+y2)+z2 d2 + stable indexed insert (ascending index order =>
// matches jax.lax.top_k ties).

#define BB 8
#define NN 8192
#define MM 2048
#define CC 256
#define EPSV 1e-8f
#define NTH 512          // 8 waves
#define NCH 8            // chunks = waves
#define CHUNK (MM/NCH)   // 256
#define PTS 64           // points per block (1 per lane)
#define MARGIN 1e-4f
#define TC 4             // channels per interp block

typedef unsigned short u16;
typedef float f16x __attribute__((ext_vector_type(16)));

// Branchy stable insert: strict < keeps lowest index on ties.
#define INS(dd, mi, D0,I0,D1,I1,D2,I2) \
    if ((dd) < D2) { \
        if ((dd) < D1) { D2 = D1; I2 = I1; \
            if ((dd) < D0) { D1 = D0; I1 = I0; D0 = (dd); I0 = (mi); } \
            else           { D1 = (dd); I1 = (mi); } \
        } else { D2 = (dd); I2 = (mi); } }

// Load 8 packed candidates (2 x 64B) into SGPRs; wait inside the asm so
// consumers can't be hoisted above the waitcnt (guide rule #18).
#define SLOAD2(A0,A1,PTR) \
    asm volatile("s_load_dwordx16 %0, %2, 0x0\n\t" \
                 "s_load_dwordx16 %1, %2, 0x40\n\t" \
                 "s_waitcnt lgkmcnt(0)" \
                 : "=s"(A0), "=s"(A1) : "s"(PTR));

// Proxy rank r = q + ax*x + ay*y + az*z (3 FMA, one SGPR operand each).
// MUST be the same expression in stage1 and stage2 (same SGPR inputs ->
// bit-identical).
#define RFE(A,J) \
    __fmaf_rn((A)[(J)*4+2], az, __fmaf_rn((A)[(J)*4+1], ay, \
              __fmaf_rn((A)[(J)*4+0], ax, (A)[(J)*4+3])))

// Stage-1 branchless 3-smallest (values only). Invariant R0<=R1<=R2.
#define S1E(A,J) { \
    const float rr = RFE(A,J); \
    R2 = __builtin_amdgcn_fmed3f(R1, R2, rr); \
    R1 = __builtin_amdgcn_fmed3f(R0, R1, rr); \
    R0 = fminf(R0, rr); }

// Stage-2 capture: exact d2 matches numpy (no FMA contraction, (x2+y2)+z2).
#define CAPX(RR,A,J,MI) \
    if ((RR) <= Tm) { \
        const float dx = ux-(A)[(J)*4+0], dy = uy-(A)[(J)*4+1], dz = uz-(A)[(J)*4+2]; \
        const float d = __fadd_rn(__fadd_rn(__fmul_rn(dx,dx),__fmul_rn(dy,dy)),__fmul_rn(dz,dz)); \
        INS(d, MI, D0,J0,D1,J1,D2,J2) }

__global__ __launch_bounds__(256) void pack_kernel(
    const float* __restrict__ known, float4* __restrict__ pack)
{
    const int i = blockIdx.x * 256 + threadIdx.x;   // over B*MM
    if (i < BB * MM) {
        const float* k = known + (size_t)i * 3;
        const float x = k[0], y = k[1], z = k[2];
        pack[i] = make_float4(x, y, z, __fmaf_rn(z, z, __fmaf_rn(y, y, x * x)));
    }
}

__global__ __launch_bounds__(NTH) void nn_scan_kernel(
    const float* __restrict__ unknown,
    const float4* __restrict__ pack,
    float4* __restrict__ wgt4,
    int4*  __restrict__ idx4)
{
    __shared__ float pd[NCH][PTS][3];     // 6 KB
    __shared__ u16   si[NCH][PTS][3];     // 3 KB
    __shared__ float Tarr[PTS];           // 256 B

    const int tilesPerBatch = NN / PTS;   // 128
    const int b    = blockIdx.x / tilesPerBatch;
    const int tile = blockIdx.x % tilesPerBatch;
    const int t    = threadIdx.x;
    const int lane = t & 63;
    const int gu   = __builtin_amdgcn_readfirstlane(t >> 6);  // wave id, uniform

    // one point per lane
    const float* u = unknown + ((size_t)b * NN + (size_t)tile * PTS + lane) * 3;
    const float ux = u[0], uy = u[1], uz = u[2];
    const float ax = -2.0f * ux, ay = -2.0f * uy, az = -2.0f * uz;

    const float4* kp0 = pack + (size_t)b * MM + gu * CHUNK;
    const int mwave = gu * CHUNK;

    // ---- stage 1: top-3 proxy values (no indices), scalar-path loads ----
    float R0 = 1e30f, R1 = 1e30f, R2 = 1e30f;
    {
        const float4* kp = kp0;
        #pragma unroll 2
        for (int grp = 0; grp < CHUNK / 8; ++grp, kp += 8) {
            f16x a0, a1;
            SLOAD2(a0, a1, kp)
            S1E(a0,0) S1E(a0,1) S1E(a0,2) S1E(a0,3)
            S1E(a1,0) S1E(a1,1) S1E(a1,2) S1E(a1,3)
        }
    }
    pd[gu][lane][0] = R0; pd[gu][lane][1] = R1; pd[gu][lane][2] = R2;
    __syncthreads();

    // ---- merge r-lists -> per-point threshold ----
    if (t < PTS) {
        float e0 = 1e30f, e1 = 1e30f, e2 = 1e30f;
        #pragma unroll
        for (int q = 0; q < NCH; ++q) {
            #pragma unroll
            for (int r = 0; r < 3; ++r) {
                const float d = pd[q][t][r];
                e2 = __builtin_amdgcn_fmed3f(e1, e2, d);
                e1 = __builtin_amdgcn_fmed3f(e0, e1, d);
                e0 = fminf(e0, d);
            }
        }
        Tarr[t] = e2 + MARGIN;
    }
    __syncthreads();

    // ---- stage 2: rescan; capture exact (d2, idx) where r <= T ----
    float D0 = 1e30f, D1 = 1e30f, D2 = 1e30f;
    int   J0 = 0,     J1 = 0,     J2 = 0;
    const float Tm = Tarr[lane];
    {
        const float4* kp = kp0;
        for (int grp = 0; grp < CHUNK / 8; ++grp, kp += 8) {
            f16x a0, a1;
            SLOAD2(a0, a1, kp)
            const int mbase = mwave + grp * 8;
            {
                const float rr0 = RFE(a0,0), rr1 = RFE(a0,1);
                const float rr2 = RFE(a0,2), rr3 = RFE(a0,3);
                if (fminf(fminf(rr0, rr1), fminf(rr2, rr3)) <= Tm) {
                    CAPX(rr0, a0,0, mbase+0)
                    CAPX(rr1, a0,1, mbase+1)
                    CAPX(rr2, a0,2, mbase+2)
                    CAPX(rr3, a0,3, mbase+3)
                }
            }
            {
                const float rr0 = RFE(a1,0), rr1 = RFE(a1,1);
                const float rr2 = RFE(a1,2), rr3 = RFE(a1,3);
                if (fminf(fminf(rr0, rr1), fminf(rr2, rr3)) <= Tm) {
                    CAPX(rr0, a1,0, mbase+4)
                    CAPX(rr1, a1,1, mbase+5)
                    CAPX(rr2, a1,2, mbase+6)
                    CAPX(rr3, a1,3, mbase+7)
                }
            }
        }
    }

    // ---- writeback captured lists + stable merge (chunk asc, rank asc) ----
    pd[gu][lane][0] = D0; pd[gu][lane][1] = D1; pd[gu][lane][2] = D2;
    si[gu][lane][0] = (u16)J0; si[gu][lane][1] = (u16)J1; si[gu][lane][2] = (u16)J2;
    __syncthreads();

    if (t < PTS) {
        float e0 = 1e30f, e1 = 1e30f, e2 = 1e30f;
        int   j0 = 0,     j1 = 0,     j2 = 0;
        #pragma unroll
        for (int q = 0; q < NCH; ++q) {     // chunk asc, rank asc => index asc
            #pragma unroll
            for (int r = 0; r < 3; ++r) {
                const float d  = pd[q][t][r];
                const int   ii = (int)si[q][t][r];
                INS(d, ii, e0,j0,e1,j1,e2,j2)
            }
        }
        const float r0 = 1.0f / (e0 + EPSV);
        const float r1 = 1.0f / (e1 + EPSV);
        const float r2 = 1.0f / (e2 + EPSV);
        const float rs = r0 + r1 + r2;
        const int gp = b * NN + tile * PTS + t;
        wgt4[gp] = make_float4(r0 / rs, r1 / rs, r2 / rs, 0.0f);
        idx4[gp] = make_int4(j0, j1, j2, 0);
    }
}

__global__ __launch_bounds__(NTH) void interp_kernel(
    const float* __restrict__ feats,
    const float4* __restrict__ wgt4,
    const int4*  __restrict__ idx4,
    float* __restrict__ out)
{
    __shared__ float fbuf[TC * MM];       // 32 KB

    const int tilesPerB = CC / TC;        // 64
    const int b  = blockIdx.x / tilesPerB;
    const int c0 = (blockIdx.x % tilesPerB) * TC;
    const int t  = threadIdx.x;

    const float4* src = reinterpret_cast<const float4*>(
        feats + ((size_t)b * CC + c0) * MM);
    #pragma unroll
    for (int i = t; i < TC * MM / 4; i += NTH)
        reinterpret_cast<float4*>(fbuf)[i] = src[i];
    __syncthreads();

    #pragma unroll 2
    for (int it = 0; it < NN / NTH; ++it) {
        const int n = it * NTH + t;
        const float4 w = wgt4[b * NN + n];
        const int4   j = idx4[b * NN + n];
        float* ob = out + ((size_t)b * CC + c0) * NN + n;
        #pragma unroll
        for (int cl = 0; cl < TC; ++cl) {
            const float* fr = fbuf + cl * MM;
            ob[(size_t)cl * NN] = w.x * fr[j.x] + w.y * fr[j.y] + w.z * fr[j.z];
        }
    }
}

extern "C" void kernel_launch(void* const* d_in, const int* in_sizes, int n_in,
                              void* d_out, int out_size, void* d_ws, size_t ws_size,
                              hipStream_t stream) {
    const float* unknown = (const float*)d_in[0];
    const float* known   = (const float*)d_in[1];
    const float* feats   = (const float*)d_in[2];
    float* out = (float*)d_out;

    float4* wgt4 = (float4*)d_ws;                                        // 1 MB
    int4*   idx4 = (int4*)((char*)d_ws + (size_t)BB * NN * sizeof(float4)); // 1 MB
    float4* pack = (float4*)((char*)d_ws + 2 * (size_t)BB * NN * 16);    // 256 KB

    pack_kernel<<<(BB * MM + 255) / 256, 256, 0, stream>>>(known, pack);
    nn_scan_kernel<<<BB * (NN / PTS), NTH, 0, stream>>>(unknown, pack, wgt4, idx4);
    interp_kernel<<<BB * (CC / TC), NTH, 0, stream>>>(feats, wgt4, idx4, out);
}